// Round 8
// baseline (179.481 us; speedup 1.0000x reference)
//
#include <hip/hip_runtime.h>
#include <math.h>

#define N_ROWS 4096
#define D_DIM  256
#define INV_T  (1.0f / 0.07f)

typedef _Float16 half8 __attribute__((ext_vector_type(8)));
typedef _Float16 half4 __attribute__((ext_vector_type(4)));
typedef float    f32x4 __attribute__((ext_vector_type(4)));
typedef unsigned long long u64;
typedef unsigned char u8;

#define GLOAD_LDS(gp, lp) \
    __builtin_amdgcn_global_load_lds( \
        (const __attribute__((address_space(1))) void*)(gp), \
        (__attribute__((address_space(3))) void*)(lp), 16, 0, 0)

// ---------------------------------------------------------------------------
// prep_k v4: normalize + mask-compress (byte layout) + accum zero.
// Round-6 post-mortem: v3's register batch was DEFEATED by the scheduler
// (VGPR=44, not ~100) -> loads still consumed incrementally, ~2-3 in flight
// per wave.  Warm replays (data fully L3-resident) ran at the SAME 47 us as
// cold ones -> pure latency/concurrency bound, not any BW wall.
// v4 forces the batch: issue the normalize load (waves 0,1) FIRST, then all
// 16 mask float4 loads, then sched_barrier(0).  Nothing may cross the fence
// -> all 16 destinations stay live (VGPR >= ~90, the verification signal).
// Normalize compute rides under the mask-load latency (its vmcnt wait only
// drains the oldest load).  M layout / perm identical to verified v3.
// (Round 7 fixed a compile error: float4 init via make_float4.)
// ---------------------------------------------------------------------------
__global__ __launch_bounds__(256) void prep_k(const float* __restrict__ f,
                                              const float* __restrict__ pm,
                                              const float* __restrict__ nm,
                                              _Float16* __restrict__ fnh,
                                              u8* __restrict__ M,
                                              float* __restrict__ accum) {
    const int t   = threadIdx.x;
    const int b   = blockIdx.x;
    const int gid = b * 256 + t;
    if (gid < 3 * N_ROWS) accum[gid] = 0.0f;

    const int lane = t & 63;
    const int w    = t >> 6;        // wave 0..3
    const int r0   = b * 2;

    const int row = r0 + (w >> 1);
    const int c0  = (w & 1) * 8;
    const float* pr = pm + (size_t)row * N_ROWS;
    const float* nr = nm + (size_t)row * N_ROWS;

    // ---- normalize load first (oldest in vmem queue): waves 0,1 only ----
    const int nrow = r0 + (w & 1);
    float4 v = make_float4(0.f, 0.f, 0.f, 0.f);
    if (w < 2) v = ((const float4*)(f + (size_t)nrow * D_DIM))[lane];

    // ---- 16 mask loads issued back-to-back ----
    float4 pv[8], nv[8];
    #pragma unroll
    for (int q = 0; q < 8; ++q) {
        const int col0 = (c0 + q) * 256 + lane * 4;
        pv[q] = *(const float4*)(pr + col0);
        nv[q] = *(const float4*)(nr + col0);
    }

    // ---- fence: no instruction may cross; the whole batch stays live ----
    __builtin_amdgcn_sched_barrier(0);

    // ---- normalize compute (waits only on the oldest load) ----
    if (w < 2) {
        float s = v.x * v.x + v.y * v.y + v.z * v.z + v.w * v.w;
        #pragma unroll
        for (int off = 32; off > 0; off >>= 1) s += __shfl_xor(s, off, 64);
        float rn = 1.0f / fmaxf(sqrtf(s), 1e-8f);
        half4 h;
        h.x = (_Float16)(v.x * rn);
        h.y = (_Float16)(v.y * rn);
        h.z = (_Float16)(v.z * rn);
        h.w = (_Float16)(v.w * rn);
        *(half4*)(fnh + (size_t)nrow * D_DIM + lane * 4) = h;
    }

    // ---- consume mask batch ----
    const int perm = (lane & 0x30) | ((lane & 3) << 2) | ((lane >> 2) & 3);
    #pragma unroll
    for (int q = 0; q < 8; ++q) {
        const int c    = c0 + q;
        const int col0 = c * 256 + lane * 4;
        float pe[4] = {pv[q].x, pv[q].y, pv[q].z, pv[q].w};
        float ne[4] = {nv[q].x, nv[q].y, nv[q].z, nv[q].w};
        unsigned bytev = 0;
        #pragma unroll
        for (int e = 0; e < 4; ++e) {
            const unsigned keep = (unsigned)(col0 + e != row);
            bytev |= (((unsigned)(pe[e] != 0.f) & keep) << e);
            bytev |= (((unsigned)(ne[e] != 0.f) & keep) << (4 + e));
        }
        M[(size_t)row * 1024 + c * 64 + perm] = (u8)bytev;
    }
}

// ---------------------------------------------------------------------------
// fused_k v12 (unchanged, verified round 6): 128x128 tile GEMM (4 waves,
// 4x4 fragments of 16x16x32, 32 KB LDS, grid 32x32) + byte-mask epilogue.
// Mask fetch per thread: ONE u32 per it (4 jt-bytes contiguous thanks to
// prep's perm): addr = M + i*1024 + (bx>>1)*64 + (bx&1)*32 + wc*16 + grp*4.
// Byte jt: bit e = P, bit 4+e = N.  16 B/thread total, M is 4 MB (L2).
// ---------------------------------------------------------------------------
__global__ __launch_bounds__(256) void fused_k(const _Float16* __restrict__ fnh,
                                               const u8* __restrict__ M,
                                               float* __restrict__ accum) {
    __shared__ __align__(16) _Float16 lds[2 * 128 * 64];   // 32 KB
    _Float16* As = lds;               // [128][64]
    _Float16* Bs = lds + 128 * 64;    // [128][64]

    const int t    = threadIdx.x;
    const int lane = t & 63;
    const int w    = t >> 6;        // wave 0..3
    const int wr   = w >> 1;        // i-half (64 rows)
    const int wc   = w & 1;         // j-half (64 cols)
    const int bx   = blockIdx.x;
    const int i0   = blockIdx.y * 128;
    const int j0   = bx * 128;
    const int l15  = lane & 15;
    const int grp  = lane >> 4;

    const int srow  = t >> 3;                          // 0..31
    const int sslot = ((t & 7) ^ ((t >> 3) & 7)) * 8;  // swizzled granule

    f32x4 acc[4][4];  // [jt][it]
    #pragma unroll
    for (int a = 0; a < 4; ++a)
        #pragma unroll
        for (int b = 0; b < 4; ++b)
            acc[a][b] = (f32x4){0.f, 0.f, 0.f, 0.f};

    for (int k0 = 0; k0 < D_DIM; k0 += 64) {
        #pragma unroll
        for (int q = 0; q < 4; ++q) {
            GLOAD_LDS(fnh + (size_t)(i0 + q * 32 + srow) * D_DIM + k0 + sslot,
                      &As[q * 2048 + w * 512]);
            GLOAD_LDS(fnh + (size_t)(j0 + q * 32 + srow) * D_DIM + k0 + sslot,
                      &Bs[q * 2048 + w * 512]);
        }
        __syncthreads();

        #pragma unroll
        for (int kk = 0; kk < 2; ++kk) {
            half8 aj[4], bi[4];
            #pragma unroll
            for (int jt = 0; jt < 4; ++jt) {
                const int r = wc * 64 + jt * 16 + l15;
                aj[jt] = *(const half8*)&Bs[r * 64 + (((kk * 4 + grp) ^ (r & 7)) << 3)];
            }
            #pragma unroll
            for (int it = 0; it < 4; ++it) {
                const int r = wr * 64 + it * 16 + l15;
                bi[it] = *(const half8*)&As[r * 64 + (((kk * 4 + grp) ^ (r & 7)) << 3)];
            }
            #pragma unroll
            for (int jt = 0; jt < 4; ++jt)
                #pragma unroll
                for (int it = 0; it < 4; ++it)
                    acc[jt][it] = __builtin_amdgcn_mfma_f32_16x16x32_f16(
                        aj[jt], bi[it], acc[jt][it], 0, 0, 0);
        }
        __syncthreads();
    }

    // ---- epilogue: one u32 mask load per it, exp/fma, reduce over grp ----
    const int    mrow0 = i0 + wr * 64 + l15;
    const size_t mcol  = (size_t)(bx >> 1) * 64 + (bx & 1) * 32 + wc * 16 + grp * 4;

    #pragma unroll
    for (int it = 0; it < 4; ++it) {
        const int i = mrow0 + it * 16;
        const unsigned mw = *(const unsigned*)(M + (size_t)i * 1024 + mcol);
        float negp = 0.f, posp = 0.f, np = 0.f;
        #pragma unroll
        for (int jt = 0; jt < 4; ++jt) {
            const unsigned byv = (mw >> (8 * jt)) & 0xFFu;
            #pragma unroll
            for (int e = 0; e < 4; ++e) {
                const float cs = acc[jt][it][e] * INV_T;
                const float pf = (float)((byv >> e) & 1u);
                const float nf = (float)((byv >> (4 + e)) & 1u);
                negp = fmaf(__expf(cs), nf, negp);
                posp = fmaf(cs, pf, posp);
                np  += pf;
            }
        }
        negp += __shfl_xor(negp, 16, 64);
        posp += __shfl_xor(posp, 16, 64);
        np   += __shfl_xor(np,   16, 64);
        negp += __shfl_xor(negp, 32, 64);
        posp += __shfl_xor(posp, 32, 64);
        np   += __shfl_xor(np,   32, 64);
        if (grp == 0) {
            atomicAdd(&accum[i], negp);
            atomicAdd(&accum[N_ROWS + i], posp);
            atomicAdd(&accum[2 * N_ROWS + i], np);
        }
    }
}

// ---------------------------------------------------------------------------
// final_k: reduction over rows -> scalar loss
// ---------------------------------------------------------------------------
__global__ __launch_bounds__(256) void final_k(const float* __restrict__ accum,
                                               float* __restrict__ out) {
    const int t = threadIdx.x;
    float s = 0.f;
    for (int i = t; i < N_ROWS; i += 256) {
        float neg  = accum[i];
        float posc = accum[N_ROWS + i];
        float np   = accum[2 * N_ROWS + i];
        float term = (np > 0.f) ? (posc - np * logf(fmaxf(neg, 1e-30f))) / np : 0.f;
        s += term;
    }
    #pragma unroll
    for (int off = 32; off > 0; off >>= 1) s += __shfl_xor(s, off, 64);
    __shared__ float wsum[4];
    if ((t & 63) == 0) wsum[t >> 6] = s;
    __syncthreads();
    if (t == 0) {
        float tot = wsum[0] + wsum[1] + wsum[2] + wsum[3];
        out[0] = -tot / (float)N_ROWS;
    }
}

// ---------------------------------------------------------------------------
// ws layout: fnh 2 MB | accum 64 KB | M 4 MB  (~6.1 MB total)
// ---------------------------------------------------------------------------
extern "C" void kernel_launch(void* const* d_in, const int* in_sizes, int n_in,
                              void* d_out, int out_size, void* d_ws, size_t ws_size,
                              hipStream_t stream) {
    const float* feat = (const float*)d_in[0];
    const float* pm   = (const float*)d_in[1];
    const float* nm   = (const float*)d_in[2];
    float* out = (float*)d_out;

    const size_t FNH_B = (size_t)N_ROWS * D_DIM * sizeof(_Float16);  // 2 MB
    const size_t ACC_B = 65536;

    _Float16* fnh = (_Float16*)d_ws;
    float* accum  = (float*)((char*)d_ws + FNH_B);
    u8* M         = (u8*)((char*)d_ws + FNH_B + ACC_B);              // 4 MB

    prep_k<<<N_ROWS / 2, 256, 0, stream>>>(feat, pm, nm, fnh, M, accum);

    dim3 grid(N_ROWS / 128, N_ROWS / 128);
    fused_k<<<grid, 256, 0, stream>>>(fnh, M, accum);

    final_k<<<1, 256, 0, stream>>>(accum, out);
}